// Round 1
// baseline (278.714 us; speedup 1.0000x reference)
//
#include <hip/hip_runtime.h>
#include <hip/hip_bf16.h>

// ---------------------------------------------------------------------------
// YOLOv3 post-processing pipeline (round 7):
//   K1 decode : plane-major coalesced feature reads; conf written in q-order
//   K3 topk   : FUSED scoring + per-class top-100 + greedy NMS.
//               Keys are computed in-register from the raw logits (float4
//               loads for layer-2 planes, scalar for layers 1/0) -- the old
//               k_score kernel and its 58 MB keybuf round-trip are gone.
//   K4 final  : per-image top-100 of 8000, rank-by-count epilogue
// ---------------------------------------------------------------------------

#define NTOT   22743      // 3*(19^2 + 38^2 + 76^2)
#define NCLS   80
#define TOPK   100
#define KPAD   22752      // row stride for conf (16B aligned, 8-div)
#define NVEC   2842       // full 8-key groups per row (22736 keys)
#define NVEC2  2166       // 8-key groups fully inside layer 2 (17328 keys)
#define Q_L1   17328
#define Q_L0   21660
#define SCORE_THR 0.2f
#define NMS_THR   0.3f

__device__ __forceinline__ float sig_exact(float x) {
    return 1.0f / (1.0f + expf(-x));          // precise OCML expf + IEEE div
}
__device__ __forceinline__ float sig_fast(float x) {
    // monotone surrogate, rel err ~1e-6 << 2^-7 bin margin
    return __builtin_amdgcn_rcpf(1.0f + __expf(-x));
}

// -------------------------- K1: decode (plane-major) ----------------------
__global__ __launch_bounds__(256) void k_decode(
    const float* __restrict__ f0, const float* __restrict__ f1,
    const float* __restrict__ f2, const float* __restrict__ anchors,
    const float* __restrict__ imshape, float4* __restrict__ boxes,
    float* __restrict__ conf_q, int total) {
    int gid = blockIdx.x * 256 + threadIdx.x;
    if (gid >= total) return;
    int b = gid / NTOT; int p = gid - b * NTOT;

    const float* f; int ghw, gw, l, off, a, s;
    if (p < 1083)      { f=f0; off=0;    ghw=361;  gw=19; l=0; int r=p;      a=r/361;  s=r-a*361;  }
    else if (p < 5415) { f=f1; off=1083; ghw=1444; gw=38; l=1; int r=p-1083; a=r/1444; s=r-a*1444; }
    else               { f=f2; off=5415; ghw=5776; gw=76; l=2; int r=p-5415; a=r/5776; s=r-a*5776; }
    int y = s / gw, x = s - y * gw;

    const float* q = f + ((size_t)(b * 255 + a * 85) * ghw + s);
    float tx = q[0], ty = q[ghw], tw = q[2*ghw], th = q[3*ghw], tc = q[4*ghw];

    int arow = (2 - l) * 3 + a;
    float aw = anchors[arow * 2], ah = anchors[arow * 2 + 1];
    float imh = imshape[0], imw = imshape[1];
    float gf = (float)gw;                       // gh == gw for all layers

    float bxx = (sig_exact(tx) + (float)x) / gf;
    float bxy = (sig_exact(ty) + (float)y) / gf;
    float bw  = expf(tw) * aw / 608.0f;
    float bh  = expf(th) * ah / 608.0f;

    float r  = fminf(608.0f / imh, 608.0f / imw);
    float nh = rintf(imh * r), nw = rintf(imw * r);
    float offy = (608.0f - nh) / 2.0f / 608.0f;
    float offx = (608.0f - nw) / 2.0f / 608.0f;
    float scy = 608.0f / nh, scx = 608.0f / nw;

    float cy = (bxy - offy) * scy;
    float cx = (bxx - offx) * scx;
    float hh = bh * scy, ww = bw * scx;

    int n = off + 3 * s + a;                    // anchor-major output index
    boxes[(size_t)b * NTOT + n] =
        make_float4((cy - hh / 2.0f) * imh, (cx - ww / 2.0f) * imw,
                    (cy + hh / 2.0f) * imh, (cx + ww / 2.0f) * imw);
    int qi = (l == 2) ? (a * 5776 + s)
           : (l == 1) ? (Q_L1 + a * 1444 + s)
                      : (Q_L0 + a * 361 + s);
    conf_q[(size_t)b * KPAD + qi] = sig_exact(tc);
}

// ------------------ shared select helpers ---------------------------------
__device__ void find_pivot(unsigned* hist, int H, unsigned target,
                           unsigned* suf, unsigned* sh_p, unsigned* sh_above) {
    const int tid = threadIdx.x;
    const int per = H >> 8;
    if (tid < 256) {
        unsigned acc = 0;
        for (int u = 0; u < per; ++u) acc += hist[tid * per + u];
        suf[tid] = acc;
    }
    __syncthreads();
    for (int off = 1; off < 256; off <<= 1) {
        unsigned v = 0;
        if (tid < 256) v = (tid + off < 256) ? suf[tid + off] : 0u;
        __syncthreads();
        if (tid < 256) suf[tid] += v;
        __syncthreads();
    }
    if (tid < 256) {
        unsigned mysuf = suf[tid];
        unsigned nxt = (tid == 255) ? 0u : suf[tid + 1];
        if (mysuf >= target && nxt < target) {
            unsigned above = nxt;
            for (int h = tid * per + per - 1; h >= tid * per; --h) {
                unsigned c2 = above + hist[h];
                if (c2 >= target) { *sh_p = (unsigned)h; *sh_above = above; break; }
                above = c2;
            }
        }
    }
    __syncthreads();
}

// q -> logit address decode (matches conf_q q-ordering)
__device__ __forceinline__ float load_logit(int b, int c, int q,
    const float* __restrict__ f0, const float* __restrict__ f1,
    const float* __restrict__ f2) {
    int a, s, ghw; const float* f;
    if (q < Q_L1)      { f = f2; ghw = 5776; a = q / 5776;  s = q - a * 5776; }
    else if (q < Q_L0) { f = f1; ghw = 1444; int r = q - Q_L1; a = r / 1444; s = r - a * 1444; }
    else               { f = f0; ghw = 361;  int r = q - Q_L0; a = r / 361;  s = r - a * 361; }
    return f[((size_t)(b * 255 + a * 85 + 5 + c)) * ghw + s];
}

__device__ __forceinline__ unsigned pack2(float cfa, float lga, float cfb, float lgb) {
    unsigned ka = __float_as_uint(cfa * sig_fast(lga)) >> 16;
    unsigned kb = __float_as_uint(cfb * sig_fast(lgb)) >> 16;
    return ka | (kb << 16);
}

// -------------------------- K3: fused score + top-100 + NMS ---------------
__device__ __forceinline__ void collect_cand(
    int b, int c, int q, const float* __restrict__ f0,
    const float* __restrict__ f1, const float* __restrict__ f2,
    const float* __restrict__ conf_q, unsigned long long* buf,
    unsigned* sh_cnt) {
    int a, s, nbase, ghw;
    const float* f;
    if (q < Q_L1)      { a = q / 5776;  s = q - a * 5776;  f = f2; ghw = 5776; nbase = 5415; }
    else if (q < Q_L0) { int r = q - Q_L1; a = r / 1444; s = r - a * 1444; f = f1; ghw = 1444; nbase = 1083; }
    else               { int r = q - Q_L0; a = r / 361;  s = r - a * 361;  f = f0; ghw = 361;  nbase = 0;    }
    float t  = f[((size_t)(b * 255 + a * 85 + 5 + c)) * ghw + s];
    float cf = conf_q[(size_t)b * KPAD + q];
    float sce = cf * sig_exact(t);
    int n = nbase + 3 * s + a;
    unsigned slot = atomicAdd(sh_cnt, 1u);
    if (slot < 512)
        buf[slot] = (((unsigned long long)__float_as_uint(sce)) << 32)
                    | (unsigned)(~n);
}

__global__ __launch_bounds__(512, 8) void k_topk(
    const float* __restrict__ f0, const float* __restrict__ f1,
    const float* __restrict__ f2, const float* __restrict__ conf_q,
    const float4* __restrict__ boxes, float4* __restrict__ top_b,
    float* __restrict__ cand) {
    __shared__ unsigned int histp[4096];           // packed u16x2: 8192 bins, 16 KB
    __shared__ unsigned long long buf[512];        // 4 KB
    __shared__ unsigned int wsum[4];
    __shared__ float sb_y1[TOPK], sb_x1[TOPK], sb_y2[TOPK], sb_x2[TOPK], sb_s[TOPK];
    __shared__ unsigned int sh_p, sh_cnt;

    const int tid = threadIdx.x;
    const int row = blockIdx.x;
    const int b = row / NCLS, c = row - b * NCLS;
    const float* cq = conf_q + (size_t)b * KPAD;

    for (int i = tid; i < 4096; i += 512) histp[i] = 0;
    if (tid == 0) sh_cnt = 0;

    // compute ALL keys in-register from logits: 6 packed uint4 (48 keys)/thread
    uint4 v[6];
    bool  val[6];
    #pragma unroll
    for (int k = 0; k < 6; ++k) {
        int g = tid + k * 512;
        val[k] = (g < NVEC);
        if (val[k]) {
            int q = g * 8;
            if (g < NVEC2) {                   // layer 2: whole group in 1 plane
                int a = q / 5776, s = q - a * 5776;
                const float* fp = f2 + ((size_t)(b * 255 + a * 85 + 5 + c)) * 5776 + s;
                float4 l0 = *(const float4*)fp;
                float4 l1 = *(const float4*)(fp + 4);
                float4 c0 = *(const float4*)(cq + q);
                float4 c1 = *(const float4*)(cq + q + 4);
                v[k].x = pack2(c0.x, l0.x, c0.y, l0.y);
                v[k].y = pack2(c0.z, l0.z, c0.w, l0.w);
                v[k].z = pack2(c1.x, l1.x, c1.y, l1.y);
                v[k].w = pack2(c1.z, l1.z, c1.w, l1.w);
            } else {                           // layers 1/0: scalar decode
                float lg[8];
                #pragma unroll
                for (int j = 0; j < 8; ++j) lg[j] = load_logit(b, c, q + j, f0, f1, f2);
                v[k].x = pack2(cq[q + 0], lg[0], cq[q + 1], lg[1]);
                v[k].y = pack2(cq[q + 2], lg[2], cq[q + 3], lg[3]);
                v[k].z = pack2(cq[q + 4], lg[4], cq[q + 5], lg[5]);
                v[k].w = pack2(cq[q + 6], lg[6], cq[q + 7], lg[7]);
            }
        } else v[k] = make_uint4(0, 0, 0, 0);
    }
    const bool hastail = (tid < NTOT - NVEC * 8);  // 7-key tail (layer 0)
    unsigned tailk = 0;
    if (hastail) {
        int q = NVEC * 8 + tid;
        tailk = __float_as_uint(cq[q] * sig_fast(load_logit(b, c, q, f0, f1, f2))) >> 16;
    }
    __syncthreads();                               // hist zeroed, sh_cnt ready

    // pass 1: packed histogram of key>>1 (8192 bins) from registers
    #pragma unroll
    for (int k = 0; k < 6; ++k) if (val[k]) {
        unsigned ks[8] = { v[k].x & 0xFFFFu, v[k].x >> 16, v[k].y & 0xFFFFu, v[k].y >> 16,
                           v[k].z & 0xFFFFu, v[k].z >> 16, v[k].w & 0xFFFFu, v[k].w >> 16 };
        #pragma unroll
        for (int j = 0; j < 8; ++j)
            atomicAdd(&histp[ks[j] >> 2], 1u << (((ks[j] >> 1) & 1u) * 16));
    }
    if (hastail) atomicAdd(&histp[tailk >> 2], 1u << (((tailk >> 1) & 1u) * 16));
    __syncthreads();

    // pivot: group t (tid<256) covers bins [t*32,t*32+32) = words [t*16,t*16+16)
    {
        const int lane = tid & 63;
        unsigned own = 0;
        if (tid < 256) {
            #pragma unroll
            for (int u = 0; u < 16; ++u) {
                unsigned w = histp[tid * 16 + u];
                own += (w & 0xFFFFu) + (w >> 16);
            }
        }
        unsigned acc = own;                        // wave-level suffix scan
        #pragma unroll
        for (int d = 1; d < 64; d <<= 1) {
            unsigned vv = __shfl_down(acc, d, 64);
            if (lane + d < 64) acc += vv;
        }
        if (tid < 256 && lane == 0) wsum[tid >> 6] = acc;
        __syncthreads();
        if (tid < 256) {
            unsigned tail = 0;
            for (int w2 = (tid >> 6) + 1; w2 < 4; ++w2) tail += wsum[w2];
            unsigned suft = acc + tail;            // suffix incl own group
            unsigned nxt  = suft - own;            // suffix of groups above
            if (suft >= TOPK && nxt < TOPK) {
                unsigned above = nxt;
                for (int bb = 31; bb >= 0; --bb) {
                    unsigned w = histp[tid * 16 + (bb >> 1)];
                    unsigned cnt = (bb & 1) ? (w >> 16) : (w & 0xFFFFu);
                    if (above + cnt >= TOPK) { sh_p = (unsigned)(tid * 32 + bb); break; }
                    above += cnt;
                }
            }
        }
        __syncthreads();
    }
    const unsigned kthr = sh_p > 0 ? ((sh_p - 1) << 1) : 0u;  // one-bin margin

    // pass 2: collect candidates FROM REGISTERS, exact rescore
    #pragma unroll
    for (int k = 0; k < 6; ++k) if (val[k]) {
        unsigned ks[8] = { v[k].x & 0xFFFFu, v[k].x >> 16, v[k].y & 0xFFFFu, v[k].y >> 16,
                           v[k].z & 0xFFFFu, v[k].z >> 16, v[k].w & 0xFFFFu, v[k].w >> 16 };
        #pragma unroll
        for (int j = 0; j < 8; ++j)
            if (ks[j] >= kthr)
                collect_cand(b, c, (tid + k * 512) * 8 + j, f0, f1, f2, conf_q, buf, &sh_cnt);
    }
    if (hastail && tailk >= kthr)
        collect_cand(b, c, NVEC * 8 + tid, f0, f1, f2, conf_q, buf, &sh_cnt);
    __syncthreads();

    // rank-by-count (keys unique: (score_bits, ~n)); M >= 100 by construction
    const int M = (int)min(sh_cnt, 512u);
    if (tid < M) {
        unsigned long long mykey = buf[tid];
        int rank = 0;
        for (int j = 0; j < M; ++j) rank += (buf[j] > mykey);   // LDS broadcast
        if (rank < TOPK) {
            int n = (int)(~(unsigned)mykey);
            float4 bx = boxes[(size_t)b * NTOT + n];
            sb_y1[rank] = bx.x; sb_x1[rank] = bx.y;
            sb_y2[rank] = bx.z; sb_x2[rank] = bx.w;
            sb_s[rank]  = __uint_as_float((unsigned)(mykey >> 32));
            top_b[(size_t)row * TOPK + rank] = bx;
        }
    }
    __syncthreads();

    // fused greedy NMS on wave 0 (reference-exact op order)
    if (tid < 64) {
        const int j0 = tid, j1 = tid + 64;
        const bool v1 = (j1 < TOPK);
        float y10 = sb_y1[j0], x10 = sb_x1[j0], y20 = sb_y2[j0], x20 = sb_x2[j0];
        float s0 = sb_s[j0];
        float y11 = v1 ? sb_y1[j1] : 0.f, x11 = v1 ? sb_x1[j1] : 0.f;
        float y21 = v1 ? sb_y2[j1] : 0.f, x21 = v1 ? sb_x2[j1] : 0.f;
        float s1 = v1 ? sb_s[j1] : -1.0f;
        float ar0 = fmaxf(y20 - y10, 0.f) * fmaxf(x20 - x10, 0.f);
        float ar1 = fmaxf(y21 - y11, 0.f) * fmaxf(x21 - x11, 0.f);
        int sup0 = 0, sup1 = 0;
        for (int i = 0; i < TOPK; ++i) {
            float yi1 = sb_y1[i], xi1 = sb_x1[i], yi2 = sb_y2[i], xi2 = sb_x2[i];
            float si = sb_s[i];
            int supi = (i < 64) ? __shfl(sup0, i, 64) : __shfl(sup1, i - 64, 64);
            bool keep_i = (si >= SCORE_THR) && (supi == 0);
            if (keep_i) {
                float ari = fmaxf(yi2 - yi1, 0.f) * fmaxf(xi2 - xi1, 0.f);
                if (j0 > i) {
                    float ty1 = fmaxf(yi1, y10), tx1 = fmaxf(xi1, x10);
                    float ty2 = fminf(yi2, y20), tx2 = fminf(xi2, x20);
                    float inter = fmaxf(ty2 - ty1, 0.f) * fmaxf(tx2 - tx1, 0.f);
                    float iou = inter / (ari + ar0 - inter + 1e-9f);
                    if (iou > NMS_THR) sup0 = 1;
                }
                if (v1 && j1 > i) {
                    float ty1 = fmaxf(yi1, y11), tx1 = fmaxf(xi1, x11);
                    float ty2 = fminf(yi2, y21), tx2 = fminf(xi2, x21);
                    float inter = fmaxf(ty2 - ty1, 0.f) * fmaxf(tx2 - tx1, 0.f);
                    float iou = inter / (ari + ar1 - inter + 1e-9f);
                    if (iou > NMS_THR) sup1 = 1;
                }
            }
        }
        cand[(size_t)row * TOPK + j0] = (s0 >= SCORE_THR && sup0 == 0) ? s0 : -1.0f;
        if (v1)
            cand[(size_t)row * TOPK + j1] = (s1 >= SCORE_THR && sup1 == 0) ? s1 : -1.0f;
    }
}

// -------------------------- K4: per-image top-100 -------------------------
__global__ __launch_bounds__(256) void k_final(
    const float* __restrict__ cand, const float4* __restrict__ top_b,
    float* __restrict__ out) {
    __shared__ float cs[8000];                     // 32 KB
    __shared__ unsigned int hist[4096];            // 16 KB
    __shared__ unsigned long long buf[512];
    __shared__ unsigned int suf[256];
    __shared__ unsigned int sh_kp, sh_p1, sh_above1, sh_p2, sh_above2, sh_cnt;

    const int tid = threadIdx.x, b = blockIdx.x;
    if (tid == 0) { sh_kp = 0; sh_cnt = 0; }
    for (int i = tid; i < 4096; i += 256) hist[i] = 0;
    __syncthreads();

    unsigned lk = 0;
    for (int i = tid; i < 8000; i += 256) {
        float v = cand[b * 8000 + i];
        cs[i] = v;
        if (v > -0.5f) lk++;
    }
    atomicAdd(&sh_kp, lk);
    __syncthreads();
    unsigned Kp = sh_kp;

    if (Kp >= TOPK) {
        for (int i = tid; i < 8000; i += 256)
            if (cs[i] > -0.5f) atomicAdd(&hist[__float_as_uint(cs[i]) >> 19], 1u);
        __syncthreads();
        find_pivot(hist, 2048, TOPK, suf, &sh_p1, &sh_above1);
        unsigned p1 = sh_p1, above1 = sh_above1;
        for (int i = tid; i < 4096; i += 256) hist[i] = 0;
        __syncthreads();
        for (int i = tid; i < 8000; i += 256) {
            float v = cs[i];
            if (v > -0.5f) {
                unsigned bits = __float_as_uint(v);
                if ((bits >> 19) == p1) atomicAdd(&hist[(bits >> 7) & 0xFFFu], 1u);
            }
        }
        __syncthreads();
        find_pivot(hist, 4096, TOPK - above1, suf, &sh_p2, &sh_above2);
        unsigned p2 = sh_p2;
        for (int i = tid; i < 8000; i += 256) {
            float v = cs[i];
            if (v > -0.5f) {
                unsigned bits = __float_as_uint(v);
                unsigned b1 = bits >> 19;
                if (b1 > p1 || (b1 == p1 && ((bits >> 7) & 0xFFFu) >= p2)) {
                    unsigned slot = atomicAdd(&sh_cnt, 1u);
                    if (slot < 512)
                        buf[slot] = (((unsigned long long)bits) << 32) | (unsigned)(~i);
                }
            }
        }
    } else {
        // < 100 kept: all kept + smallest flat indices among exact -1.0 ties
        for (int i = tid; i < 8000; i += 256) {
            float v = cs[i];
            if (v > -0.5f) {
                unsigned slot = atomicAdd(&sh_cnt, 1u);
                buf[slot] = (((unsigned long long)__float_as_uint(v)) << 32) | (unsigned)(~i);
            }
        }
        __syncthreads();
        if (tid == 0) {
            unsigned need = TOPK - Kp, got = 0;
            for (int i = 0; i < 8000 && got < need; ++i)
                if (cs[i] <= -0.5f) { buf[Kp + got] = (unsigned)(~i); got++; }
        }
    }
    __syncthreads();

    // rank-by-count epilogue (keys unique via distinct ~i)
    const int M2 = (Kp >= TOPK) ? (int)min(sh_cnt, 512u) : (int)TOPK;
    for (int i = tid; i < M2; i += 256) {
        unsigned long long key = buf[i];
        int rank = 0;
        for (int j = 0; j < M2; ++j) rank += (buf[j] > key);
        if (rank < TOPK) {
            int fi = (int)(~(unsigned)key);
            int c = fi / TOPK; int kk = fi - c * TOPK;
            float4 bb = top_b[((size_t)b * NCLS + c) * TOPK + kk];
            int base = (b * TOPK + rank) * 6;
            out[base + 0] = bb.x; out[base + 1] = bb.y;
            out[base + 2] = bb.z; out[base + 3] = bb.w;
            out[base + 4] = cs[fi]; out[base + 5] = (float)c;
        }
    }
}

// ---------------------------------------------------------------------------
extern "C" void kernel_launch(void* const* d_in, const int* in_sizes, int n_in,
                              void* d_out, int out_size, void* d_ws, size_t ws_size,
                              hipStream_t stream) {
    (void)n_in; (void)out_size; (void)ws_size;
    const float* f0      = (const float*)d_in[0];
    const float* f1      = (const float*)d_in[1];
    const float* f2      = (const float*)d_in[2];
    const float* anchors = (const float*)d_in[3];
    const float* imshape = (const float*)d_in[4];
    const int B = in_sizes[0] / (255 * 19 * 19);

    char* ws = (char*)d_ws;
    size_t o = 0;
    float4* boxes  = (float4*)(ws + o); o += (size_t)B * NTOT * sizeof(float4);
    float*  conf_q = (float*)(ws + o);  o += (size_t)B * KPAD * sizeof(float);
    float4* top_b  = (float4*)(ws + o); o += (size_t)B * NCLS * TOPK * sizeof(float4);
    float*  cand   = (float*)(ws + o);  o += (size_t)B * NCLS * TOPK * sizeof(float);
    float*  out    = (float*)d_out;

    const int total = B * NTOT;
    k_decode<<<(total + 255) / 256, 256, 0, stream>>>(f0, f1, f2, anchors, imshape,
                                                      boxes, conf_q, total);
    k_topk<<<B * NCLS, 512, 0, stream>>>(f0, f1, f2, conf_q, boxes,
                                         top_b, cand);
    k_final<<<B, 256, 0, stream>>>(cand, top_b, out);
}

// Round 2
// 262.001 us; speedup vs baseline: 1.0638x; 1.0638x over previous
//
#include <hip/hip_runtime.h>
#include <hip/hip_bf16.h>

// ---------------------------------------------------------------------------
// YOLOv3 post-processing pipeline (round 8):
//   K1 decode : plane-major coalesced feature reads; conf written in q-order
//   K3 topk   : FUSED scoring + per-class top-100 + greedy NMS.
//               Keys computed in-register from raw logits. Round-7 lesson:
//               __launch_bounds__(512,8) capped VGPRs at 64 -> the 24-VGPR
//               key cache spilled to scratch (82 MB HBM writes). Now (512,4)
//               = 128-VGPR cap, keys stay in registers. Layer-1 logit loads
//               vectorized (planes 16B-aligned); layer-0 stays scalar.
//   K4 final  : per-image top-100 of 8000, rank-by-count epilogue
// ---------------------------------------------------------------------------

#define NTOT   22743      // 3*(19^2 + 38^2 + 76^2)
#define NCLS   80
#define TOPK   100
#define KPAD   22752      // row stride for conf (16B aligned, 8-div)
#define NVEC   2842       // full 8-key groups per row (22736 keys)
#define Q_L1   17328
#define Q_L0   21660
#define SCORE_THR 0.2f
#define NMS_THR   0.3f

__device__ __forceinline__ float sig_exact(float x) {
    return 1.0f / (1.0f + expf(-x));          // precise OCML expf + IEEE div
}
__device__ __forceinline__ float sig_fast(float x) {
    // monotone surrogate, rel err ~1e-6 << 2^-7 bin margin
    return __builtin_amdgcn_rcpf(1.0f + __expf(-x));
}

// -------------------------- K1: decode (plane-major) ----------------------
__global__ __launch_bounds__(256) void k_decode(
    const float* __restrict__ f0, const float* __restrict__ f1,
    const float* __restrict__ f2, const float* __restrict__ anchors,
    const float* __restrict__ imshape, float4* __restrict__ boxes,
    float* __restrict__ conf_q, int total) {
    int gid = blockIdx.x * 256 + threadIdx.x;
    if (gid >= total) return;
    int b = gid / NTOT; int p = gid - b * NTOT;

    const float* f; int ghw, gw, l, off, a, s;
    if (p < 1083)      { f=f0; off=0;    ghw=361;  gw=19; l=0; int r=p;      a=r/361;  s=r-a*361;  }
    else if (p < 5415) { f=f1; off=1083; ghw=1444; gw=38; l=1; int r=p-1083; a=r/1444; s=r-a*1444; }
    else               { f=f2; off=5415; ghw=5776; gw=76; l=2; int r=p-5415; a=r/5776; s=r-a*5776; }
    int y = s / gw, x = s - y * gw;

    const float* q = f + ((size_t)(b * 255 + a * 85) * ghw + s);
    float tx = q[0], ty = q[ghw], tw = q[2*ghw], th = q[3*ghw], tc = q[4*ghw];

    int arow = (2 - l) * 3 + a;
    float aw = anchors[arow * 2], ah = anchors[arow * 2 + 1];
    float imh = imshape[0], imw = imshape[1];
    float gf = (float)gw;                       // gh == gw for all layers

    float bxx = (sig_exact(tx) + (float)x) / gf;
    float bxy = (sig_exact(ty) + (float)y) / gf;
    float bw  = expf(tw) * aw / 608.0f;
    float bh  = expf(th) * ah / 608.0f;

    float r  = fminf(608.0f / imh, 608.0f / imw);
    float nh = rintf(imh * r), nw = rintf(imw * r);
    float offy = (608.0f - nh) / 2.0f / 608.0f;
    float offx = (608.0f - nw) / 2.0f / 608.0f;
    float scy = 608.0f / nh, scx = 608.0f / nw;

    float cy = (bxy - offy) * scy;
    float cx = (bxx - offx) * scx;
    float hh = bh * scy, ww = bw * scx;

    int n = off + 3 * s + a;                    // anchor-major output index
    boxes[(size_t)b * NTOT + n] =
        make_float4((cy - hh / 2.0f) * imh, (cx - ww / 2.0f) * imw,
                    (cy + hh / 2.0f) * imh, (cx + ww / 2.0f) * imw);
    int qi = (l == 2) ? (a * 5776 + s)
           : (l == 1) ? (Q_L1 + a * 1444 + s)
                      : (Q_L0 + a * 361 + s);
    conf_q[(size_t)b * KPAD + qi] = sig_exact(tc);
}

// ------------------ shared select helpers ---------------------------------
__device__ void find_pivot(unsigned* hist, int H, unsigned target,
                           unsigned* suf, unsigned* sh_p, unsigned* sh_above) {
    const int tid = threadIdx.x;
    const int per = H >> 8;
    if (tid < 256) {
        unsigned acc = 0;
        for (int u = 0; u < per; ++u) acc += hist[tid * per + u];
        suf[tid] = acc;
    }
    __syncthreads();
    for (int off = 1; off < 256; off <<= 1) {
        unsigned v = 0;
        if (tid < 256) v = (tid + off < 256) ? suf[tid + off] : 0u;
        __syncthreads();
        if (tid < 256) suf[tid] += v;
        __syncthreads();
    }
    if (tid < 256) {
        unsigned mysuf = suf[tid];
        unsigned nxt = (tid == 255) ? 0u : suf[tid + 1];
        if (mysuf >= target && nxt < target) {
            unsigned above = nxt;
            for (int h = tid * per + per - 1; h >= tid * per; --h) {
                unsigned c2 = above + hist[h];
                if (c2 >= target) { *sh_p = (unsigned)h; *sh_above = above; break; }
                above = c2;
            }
        }
    }
    __syncthreads();
}

// q -> logit address decode (matches conf_q q-ordering)
__device__ __forceinline__ float load_logit(int b, int c, int q,
    const float* __restrict__ f0, const float* __restrict__ f1,
    const float* __restrict__ f2) {
    int a, s, ghw; const float* f;
    if (q < Q_L1)      { f = f2; ghw = 5776; a = q / 5776;  s = q - a * 5776; }
    else if (q < Q_L0) { f = f1; ghw = 1444; int r = q - Q_L1; a = r / 1444; s = r - a * 1444; }
    else               { f = f0; ghw = 361;  int r = q - Q_L0; a = r / 361;  s = r - a * 361; }
    return f[((size_t)(b * 255 + a * 85 + 5 + c)) * ghw + s];
}

__device__ __forceinline__ unsigned pack2(float cfa, float lga, float cfb, float lgb) {
    unsigned ka = __float_as_uint(cfa * sig_fast(lga)) >> 16;
    unsigned kb = __float_as_uint(cfb * sig_fast(lgb)) >> 16;
    return ka | (kb << 16);
}

// -------------------------- K3: fused score + top-100 + NMS ---------------
__device__ __forceinline__ void collect_cand(
    int b, int c, int q, const float* __restrict__ f0,
    const float* __restrict__ f1, const float* __restrict__ f2,
    const float* __restrict__ conf_q, unsigned long long* buf,
    unsigned* sh_cnt) {
    int a, s, nbase, ghw;
    const float* f;
    if (q < Q_L1)      { a = q / 5776;  s = q - a * 5776;  f = f2; ghw = 5776; nbase = 5415; }
    else if (q < Q_L0) { int r = q - Q_L1; a = r / 1444; s = r - a * 1444; f = f1; ghw = 1444; nbase = 1083; }
    else               { int r = q - Q_L0; a = r / 361;  s = r - a * 361;  f = f0; ghw = 361;  nbase = 0;    }
    float t  = f[((size_t)(b * 255 + a * 85 + 5 + c)) * ghw + s];
    float cf = conf_q[(size_t)b * KPAD + q];
    float sce = cf * sig_exact(t);
    int n = nbase + 3 * s + a;
    unsigned slot = atomicAdd(sh_cnt, 1u);
    if (slot < 512)
        buf[slot] = (((unsigned long long)__float_as_uint(sce)) << 32)
                    | (unsigned)(~n);
}

__global__ __launch_bounds__(512, 4) void k_topk(
    const float* __restrict__ f0, const float* __restrict__ f1,
    const float* __restrict__ f2, const float* __restrict__ conf_q,
    const float4* __restrict__ boxes, float4* __restrict__ top_b,
    float* __restrict__ cand) {
    __shared__ unsigned int histp[4096];           // packed u16x2: 8192 bins, 16 KB
    __shared__ unsigned long long buf[512];        // 4 KB
    __shared__ unsigned int wsum[4];
    __shared__ float sb_y1[TOPK], sb_x1[TOPK], sb_y2[TOPK], sb_x2[TOPK], sb_s[TOPK];
    __shared__ unsigned int sh_p, sh_cnt;

    const int tid = threadIdx.x;
    const int row = blockIdx.x;
    const int b = row / NCLS, c = row - b * NCLS;
    const float* cq = conf_q + (size_t)b * KPAD;

    for (int i = tid; i < 4096; i += 512) histp[i] = 0;
    if (tid == 0) sh_cnt = 0;

    // compute ALL keys in-register from logits: 6 packed uint4 (48 keys)/thread
    uint4 v[6];
    bool  val[6];
    #pragma unroll
    for (int k = 0; k < 6; ++k) {
        int g = tid + k * 512;
        val[k] = (g < NVEC);
        if (val[k]) {
            int q = g * 8;
            const float* fp = nullptr;
            if (q < Q_L1) {                    // layer 2: 5776%8==0, always whole
                int a = q / 5776, s = q - a * 5776;
                fp = f2 + ((size_t)(b * 255 + a * 85 + 5 + c)) * 5776 + s;
            } else if (q + 8 <= Q_L0) {        // layer 1: 16B-aligned planes
                int r = q - Q_L1; int a = r / 1444, s = r - a * 1444;
                if (s + 8 <= 1444)
                    fp = f1 + ((size_t)(b * 255 + a * 85 + 5 + c)) * 1444 + s;
            }                                  // layer 0 planes not 16B-aligned
            if (fp) {                          // vector path: 2x float4 + 2x float4
                float4 l0 = *(const float4*)fp;
                float4 l1 = *(const float4*)(fp + 4);
                float4 c0 = *(const float4*)(cq + q);
                float4 c1 = *(const float4*)(cq + q + 4);
                v[k].x = pack2(c0.x, l0.x, c0.y, l0.y);
                v[k].y = pack2(c0.z, l0.z, c0.w, l0.w);
                v[k].z = pack2(c1.x, l1.x, c1.y, l1.y);
                v[k].w = pack2(c1.z, l1.z, c1.w, l1.w);
            } else {                           // scalar fallback (layer 0 + seams)
                float lg[8];
                #pragma unroll
                for (int j = 0; j < 8; ++j) lg[j] = load_logit(b, c, q + j, f0, f1, f2);
                v[k].x = pack2(cq[q + 0], lg[0], cq[q + 1], lg[1]);
                v[k].y = pack2(cq[q + 2], lg[2], cq[q + 3], lg[3]);
                v[k].z = pack2(cq[q + 4], lg[4], cq[q + 5], lg[5]);
                v[k].w = pack2(cq[q + 6], lg[6], cq[q + 7], lg[7]);
            }
        } else v[k] = make_uint4(0, 0, 0, 0);
    }
    const bool hastail = (tid < NTOT - NVEC * 8);  // 7-key tail (layer 0)
    unsigned tailk = 0;
    if (hastail) {
        int q = NVEC * 8 + tid;
        tailk = __float_as_uint(cq[q] * sig_fast(load_logit(b, c, q, f0, f1, f2))) >> 16;
    }
    __syncthreads();                               // hist zeroed, sh_cnt ready

    // pass 1: packed histogram of key>>1 (8192 bins) from registers
    #pragma unroll
    for (int k = 0; k < 6; ++k) if (val[k]) {
        unsigned ks[8] = { v[k].x & 0xFFFFu, v[k].x >> 16, v[k].y & 0xFFFFu, v[k].y >> 16,
                           v[k].z & 0xFFFFu, v[k].z >> 16, v[k].w & 0xFFFFu, v[k].w >> 16 };
        #pragma unroll
        for (int j = 0; j < 8; ++j)
            atomicAdd(&histp[ks[j] >> 2], 1u << (((ks[j] >> 1) & 1u) * 16));
    }
    if (hastail) atomicAdd(&histp[tailk >> 2], 1u << (((tailk >> 1) & 1u) * 16));
    __syncthreads();

    // pivot: group t (tid<256) covers bins [t*32,t*32+32) = words [t*16,t*16+16)
    {
        const int lane = tid & 63;
        unsigned own = 0;
        if (tid < 256) {
            #pragma unroll
            for (int u = 0; u < 16; ++u) {
                unsigned w = histp[tid * 16 + u];
                own += (w & 0xFFFFu) + (w >> 16);
            }
        }
        unsigned acc = own;                        // wave-level suffix scan
        #pragma unroll
        for (int d = 1; d < 64; d <<= 1) {
            unsigned vv = __shfl_down(acc, d, 64);
            if (lane + d < 64) acc += vv;
        }
        if (tid < 256 && lane == 0) wsum[tid >> 6] = acc;
        __syncthreads();
        if (tid < 256) {
            unsigned tail = 0;
            for (int w2 = (tid >> 6) + 1; w2 < 4; ++w2) tail += wsum[w2];
            unsigned suft = acc + tail;            // suffix incl own group
            unsigned nxt  = suft - own;            // suffix of groups above
            if (suft >= TOPK && nxt < TOPK) {
                unsigned above = nxt;
                for (int bb = 31; bb >= 0; --bb) {
                    unsigned w = histp[tid * 16 + (bb >> 1)];
                    unsigned cnt = (bb & 1) ? (w >> 16) : (w & 0xFFFFu);
                    if (above + cnt >= TOPK) { sh_p = (unsigned)(tid * 32 + bb); break; }
                    above += cnt;
                }
            }
        }
        __syncthreads();
    }
    const unsigned kthr = sh_p > 0 ? ((sh_p - 1) << 1) : 0u;  // one-bin margin

    // pass 2: collect candidates FROM REGISTERS, exact rescore
    #pragma unroll
    for (int k = 0; k < 6; ++k) if (val[k]) {
        unsigned ks[8] = { v[k].x & 0xFFFFu, v[k].x >> 16, v[k].y & 0xFFFFu, v[k].y >> 16,
                           v[k].z & 0xFFFFu, v[k].z >> 16, v[k].w & 0xFFFFu, v[k].w >> 16 };
        #pragma unroll
        for (int j = 0; j < 8; ++j)
            if (ks[j] >= kthr)
                collect_cand(b, c, (tid + k * 512) * 8 + j, f0, f1, f2, conf_q, buf, &sh_cnt);
    }
    if (hastail && tailk >= kthr)
        collect_cand(b, c, NVEC * 8 + tid, f0, f1, f2, conf_q, buf, &sh_cnt);
    __syncthreads();

    // rank-by-count (keys unique: (score_bits, ~n)); M >= 100 by construction
    const int M = (int)min(sh_cnt, 512u);
    if (tid < M) {
        unsigned long long mykey = buf[tid];
        int rank = 0;
        for (int j = 0; j < M; ++j) rank += (buf[j] > mykey);   // LDS broadcast
        if (rank < TOPK) {
            int n = (int)(~(unsigned)mykey);
            float4 bx = boxes[(size_t)b * NTOT + n];
            sb_y1[rank] = bx.x; sb_x1[rank] = bx.y;
            sb_y2[rank] = bx.z; sb_x2[rank] = bx.w;
            sb_s[rank]  = __uint_as_float((unsigned)(mykey >> 32));
            top_b[(size_t)row * TOPK + rank] = bx;
        }
    }
    __syncthreads();

    // fused greedy NMS on wave 0 (reference-exact op order)
    if (tid < 64) {
        const int j0 = tid, j1 = tid + 64;
        const bool v1 = (j1 < TOPK);
        float y10 = sb_y1[j0], x10 = sb_x1[j0], y20 = sb_y2[j0], x20 = sb_x2[j0];
        float s0 = sb_s[j0];
        float y11 = v1 ? sb_y1[j1] : 0.f, x11 = v1 ? sb_x1[j1] : 0.f;
        float y21 = v1 ? sb_y2[j1] : 0.f, x21 = v1 ? sb_x2[j1] : 0.f;
        float s1 = v1 ? sb_s[j1] : -1.0f;
        float ar0 = fmaxf(y20 - y10, 0.f) * fmaxf(x20 - x10, 0.f);
        float ar1 = fmaxf(y21 - y11, 0.f) * fmaxf(x21 - x11, 0.f);
        int sup0 = 0, sup1 = 0;
        for (int i = 0; i < TOPK; ++i) {
            float yi1 = sb_y1[i], xi1 = sb_x1[i], yi2 = sb_y2[i], xi2 = sb_x2[i];
            float si = sb_s[i];
            int supi = (i < 64) ? __shfl(sup0, i, 64) : __shfl(sup1, i - 64, 64);
            bool keep_i = (si >= SCORE_THR) && (supi == 0);
            if (keep_i) {
                float ari = fmaxf(yi2 - yi1, 0.f) * fmaxf(xi2 - xi1, 0.f);
                if (j0 > i) {
                    float ty1 = fmaxf(yi1, y10), tx1 = fmaxf(xi1, x10);
                    float ty2 = fminf(yi2, y20), tx2 = fminf(xi2, x20);
                    float inter = fmaxf(ty2 - ty1, 0.f) * fmaxf(tx2 - tx1, 0.f);
                    float iou = inter / (ari + ar0 - inter + 1e-9f);
                    if (iou > NMS_THR) sup0 = 1;
                }
                if (v1 && j1 > i) {
                    float ty1 = fmaxf(yi1, y11), tx1 = fmaxf(xi1, x11);
                    float ty2 = fminf(yi2, y21), tx2 = fminf(xi2, x21);
                    float inter = fmaxf(ty2 - ty1, 0.f) * fmaxf(tx2 - tx1, 0.f);
                    float iou = inter / (ari + ar1 - inter + 1e-9f);
                    if (iou > NMS_THR) sup1 = 1;
                }
            }
        }
        cand[(size_t)row * TOPK + j0] = (s0 >= SCORE_THR && sup0 == 0) ? s0 : -1.0f;
        if (v1)
            cand[(size_t)row * TOPK + j1] = (s1 >= SCORE_THR && sup1 == 0) ? s1 : -1.0f;
    }
}

// -------------------------- K4: per-image top-100 -------------------------
__global__ __launch_bounds__(256) void k_final(
    const float* __restrict__ cand, const float4* __restrict__ top_b,
    float* __restrict__ out) {
    __shared__ float cs[8000];                     // 32 KB
    __shared__ unsigned int hist[4096];            // 16 KB
    __shared__ unsigned long long buf[512];
    __shared__ unsigned int suf[256];
    __shared__ unsigned int sh_kp, sh_p1, sh_above1, sh_p2, sh_above2, sh_cnt;

    const int tid = threadIdx.x, b = blockIdx.x;
    if (tid == 0) { sh_kp = 0; sh_cnt = 0; }
    for (int i = tid; i < 4096; i += 256) hist[i] = 0;
    __syncthreads();

    unsigned lk = 0;
    for (int i = tid; i < 8000; i += 256) {
        float v = cand[b * 8000 + i];
        cs[i] = v;
        if (v > -0.5f) lk++;
    }
    atomicAdd(&sh_kp, lk);
    __syncthreads();
    unsigned Kp = sh_kp;

    if (Kp >= TOPK) {
        for (int i = tid; i < 8000; i += 256)
            if (cs[i] > -0.5f) atomicAdd(&hist[__float_as_uint(cs[i]) >> 19], 1u);
        __syncthreads();
        find_pivot(hist, 2048, TOPK, suf, &sh_p1, &sh_above1);
        unsigned p1 = sh_p1, above1 = sh_above1;
        for (int i = tid; i < 4096; i += 256) hist[i] = 0;
        __syncthreads();
        for (int i = tid; i < 8000; i += 256) {
            float v = cs[i];
            if (v > -0.5f) {
                unsigned bits = __float_as_uint(v);
                if ((bits >> 19) == p1) atomicAdd(&hist[(bits >> 7) & 0xFFFu], 1u);
            }
        }
        __syncthreads();
        find_pivot(hist, 4096, TOPK - above1, suf, &sh_p2, &sh_above2);
        unsigned p2 = sh_p2;
        for (int i = tid; i < 8000; i += 256) {
            float v = cs[i];
            if (v > -0.5f) {
                unsigned bits = __float_as_uint(v);
                unsigned b1 = bits >> 19;
                if (b1 > p1 || (b1 == p1 && ((bits >> 7) & 0xFFFu) >= p2)) {
                    unsigned slot = atomicAdd(&sh_cnt, 1u);
                    if (slot < 512)
                        buf[slot] = (((unsigned long long)bits) << 32) | (unsigned)(~i);
                }
            }
        }
    } else {
        // < 100 kept: all kept + smallest flat indices among exact -1.0 ties
        for (int i = tid; i < 8000; i += 256) {
            float v = cs[i];
            if (v > -0.5f) {
                unsigned slot = atomicAdd(&sh_cnt, 1u);
                buf[slot] = (((unsigned long long)__float_as_uint(v)) << 32) | (unsigned)(~i);
            }
        }
        __syncthreads();
        if (tid == 0) {
            unsigned need = TOPK - Kp, got = 0;
            for (int i = 0; i < 8000 && got < need; ++i)
                if (cs[i] <= -0.5f) { buf[Kp + got] = (unsigned)(~i); got++; }
        }
    }
    __syncthreads();

    // rank-by-count epilogue (keys unique via distinct ~i)
    const int M2 = (Kp >= TOPK) ? (int)min(sh_cnt, 512u) : (int)TOPK;
    for (int i = tid; i < M2; i += 256) {
        unsigned long long key = buf[i];
        int rank = 0;
        for (int j = 0; j < M2; ++j) rank += (buf[j] > key);
        if (rank < TOPK) {
            int fi = (int)(~(unsigned)key);
            int c = fi / TOPK; int kk = fi - c * TOPK;
            float4 bb = top_b[((size_t)b * NCLS + c) * TOPK + kk];
            int base = (b * TOPK + rank) * 6;
            out[base + 0] = bb.x; out[base + 1] = bb.y;
            out[base + 2] = bb.z; out[base + 3] = bb.w;
            out[base + 4] = cs[fi]; out[base + 5] = (float)c;
        }
    }
}

// ---------------------------------------------------------------------------
extern "C" void kernel_launch(void* const* d_in, const int* in_sizes, int n_in,
                              void* d_out, int out_size, void* d_ws, size_t ws_size,
                              hipStream_t stream) {
    (void)n_in; (void)out_size; (void)ws_size;
    const float* f0      = (const float*)d_in[0];
    const float* f1      = (const float*)d_in[1];
    const float* f2      = (const float*)d_in[2];
    const float* anchors = (const float*)d_in[3];
    const float* imshape = (const float*)d_in[4];
    const int B = in_sizes[0] / (255 * 19 * 19);

    char* ws = (char*)d_ws;
    size_t o = 0;
    float4* boxes  = (float4*)(ws + o); o += (size_t)B * NTOT * sizeof(float4);
    float*  conf_q = (float*)(ws + o);  o += (size_t)B * KPAD * sizeof(float);
    float4* top_b  = (float4*)(ws + o); o += (size_t)B * NCLS * TOPK * sizeof(float4);
    float*  cand   = (float*)(ws + o);  o += (size_t)B * NCLS * TOPK * sizeof(float);
    float*  out    = (float*)d_out;

    const int total = B * NTOT;
    k_decode<<<(total + 255) / 256, 256, 0, stream>>>(f0, f1, f2, anchors, imshape,
                                                      boxes, conf_q, total);
    k_topk<<<B * NCLS, 512, 0, stream>>>(f0, f1, f2, conf_q, boxes,
                                         top_b, cand);
    k_final<<<B, 256, 0, stream>>>(cand, top_b, out);
}